// Round 1
// baseline (694.735 us; speedup 1.0000x reference)
//
#include <hip/hip_runtime.h>

// Projector: img[b,h,w] = sum_a coef_a * exp(-(h_c-y)^2/(2 var)) * exp(-(w_c-x)^2/(2 var))
// coord[i] = i - 63.5 (S=128, res=1.0). stds in [0.5,1.5) => Gaussian support ~ +/-10 px.
// Strategy: per-atom 21x21 patch scatter into LDS-privatized per-(batch,chunk) image,
// then global atomicAdd into zeroed d_out.

#define S 128
#define RADI 10          // integer patch half-width
#define WMAX 21          // max patch width
#define NSPLIT 32        // atom-chunks per batch image
#define BLOCK 256

__global__ __launch_bounds__(BLOCK) void proj_kernel(
    const float* __restrict__ mol,   // (B, A, 3)
    const float* __restrict__ stds,  // (A)
    const float* __restrict__ dens,  // (A)
    float* __restrict__ out,         // (B, S, S) fp32, pre-zeroed
    int B, int A)
{
    __shared__ float simg[S * S];    // 64 KB private partial image

    const int b     = blockIdx.x / NSPLIT;
    const int split = blockIdx.x % NSPLIT;
    const int tid   = threadIdx.x;

    for (int i = tid; i < S * S; i += BLOCK) simg[i] = 0.0f;
    __syncthreads();

    const int chunk = (A + NSPLIT - 1) / NSPLIT;
    const int a0 = split * chunk;
    const int a1 = (a0 + chunk < A) ? (a0 + chunk) : A;

    for (int a = a0 + tid; a < a1; a += BLOCK) {
        const float x  = mol[(size_t)(b * A + a) * 3 + 0];
        const float y  = mol[(size_t)(b * A + a) * 3 + 1];
        const float sd = stds[a];
        const float var  = sd * sd;
        const float ninv = -0.5f / var;
        const float coef = dens[a] * 0.15915494309189535f / var;  // d/(2*pi*var)

        const float cx = x + 63.5f;   // pixel-space center
        const float cy = y + 63.5f;

        int w0 = (int)ceilf(cx - (float)RADI);  if (w0 < 0) w0 = 0;
        int w1 = (int)floorf(cx + (float)RADI); if (w1 > S - 1) w1 = S - 1;
        int h0 = (int)ceilf(cy - (float)RADI);  if (h0 < 0) h0 = 0;
        int h1 = (int)floorf(cy + (float)RADI); if (h1 > S - 1) h1 = S - 1;
        if (w0 > w1 || h0 > h1) continue;       // atom outside FOV reach

        // Separable x-profile, fully unrolled so gx[] stays in VGPRs.
        float gx[WMAX];
#pragma unroll
        for (int i = 0; i < WMAX; ++i) {
            float d = (float)(w0 + i) - 63.5f - x;
            gx[i] = __expf(ninv * d * d);
        }

        for (int h = h0; h <= h1; ++h) {
            float dy  = (float)h - 63.5f - y;
            float gyc = coef * __expf(ninv * dy * dy);
            float* row = simg + h * S;
#pragma unroll
            for (int i = 0; i < WMAX; ++i) {
                int w = w0 + i;
                if (w <= w1) atomicAdd(&row[w], gyc * gx[i]);  // ds_add_f32
            }
        }
    }

    __syncthreads();

    // Flush partial image to global (d_out zeroed by kernel_launch).
    const size_t ob = (size_t)b * S * S;
    for (int i = tid; i < S * S; i += BLOCK) {
        float v = simg[i];
        if (v != 0.0f) atomicAdd(&out[ob + i], v);
    }
}

extern "C" void kernel_launch(void* const* d_in, const int* in_sizes, int n_in,
                              void* d_out, int out_size, void* d_ws, size_t ws_size,
                              hipStream_t stream) {
    const float* mol  = (const float*)d_in[0];
    const float* stds = (const float*)d_in[1];
    const float* dens = (const float*)d_in[2];
    float* out = (float*)d_out;

    const int A = in_sizes[1];             // 20000
    const int B = in_sizes[0] / (A * 3);   // 16

    hipMemsetAsync(d_out, 0, (size_t)out_size * sizeof(float), stream);
    proj_kernel<<<dim3(B * NSPLIT), dim3(BLOCK), 0, stream>>>(mol, stds, dens, out, B, A);
}

// Round 2
// 268.397 us; speedup vs baseline: 2.5885x; 2.5885x over previous
//
#include <hip/hip_runtime.h>

// Gather formulation: img[b,h,w] = sum_a coef_a * exp(ninv*((w_c-x)^2+(h_c-y)^2))
// Each block = (batch b, 16x16 pixel tile, atom-split). Thread = one pixel,
// register accumulator. Atoms bbox-filtered + ballot-compacted into LDS, then
// one fused exp2 per atom-pixel. No LDS atomics (R1 showed ds_add_f32 ~ 2.8 cy/lane
// => 645us floor); only ~2M global atomics to merge the NS partial tiles.

#define S 128
#define TS 16
#define TPS (S / TS)            // tiles per side = 8
#define NTILE (TPS * TPS)       // 64
#define NS 8                    // atom-splits per tile (load balance)
#define BLOCK 256
#define RAD 6.5f                // truncation radius: err ~ 8*exp(-6.5^2/4.5) ~ 7e-4

__global__ __launch_bounds__(BLOCK) void proj_gather(
    const float* __restrict__ mol,   // (B, A, 3)
    const float* __restrict__ stds,  // (A)
    const float* __restrict__ dens,  // (A)
    float* __restrict__ out,         // (B, S, S) fp32, pre-zeroed
    int A)
{
    __shared__ float4 satom[BLOCK];  // compacted (x, y, k, c2)
    __shared__ int s_cnt;

    const int tile  = blockIdx.x;
    const int split = blockIdx.y;
    const int b     = blockIdx.z;

    const int tx0 = (tile & (TPS - 1)) * TS;
    const int ty0 = (tile / TPS) * TS;
    const int tid  = threadIdx.x;
    const int lane = tid & 63;

    const int px = tx0 + (tid & (TS - 1));
    const int py = ty0 + (tid / TS);
    const float pxf = (float)px - 63.5f;   // pixel-center coordinate
    const float pyf = (float)py - 63.5f;

    // tile bbox in atom-coordinate space, expanded by RAD
    const float xlo = (float)tx0 - 63.5f - RAD;
    const float xhi = (float)(tx0 + TS - 1) - 63.5f + RAD;
    const float ylo = (float)ty0 - 63.5f - RAD;
    const float yhi = (float)(ty0 + TS - 1) - 63.5f + RAD;

    const int per = (A + NS - 1) / NS;
    const int a0 = split * per;
    const int a1 = min(a0 + per, A);

    const size_t molbase = (size_t)b * A;

    float acc = 0.0f;

    for (int base = a0; base < a1; base += BLOCK) {
        if (tid == 0) s_cnt = 0;
        __syncthreads();

        const int a = base + tid;
        bool ok = false;
        float x = 0.0f, y = 0.0f;
        if (a < a1) {
            x = mol[(molbase + a) * 3 + 0];
            y = mol[(molbase + a) * 3 + 1];
            ok = (x >= xlo) && (x <= xhi) && (y >= ylo) && (y <= yhi);
        }

        // wave-level ballot compaction into LDS
        unsigned long long m = __ballot(ok);
        int wb = 0;
        if (lane == 0 && m) wb = atomicAdd(&s_cnt, __popcll(m));
        wb = __shfl(wb, 0);
        if (ok) {
            int pos = wb + __popcll(m & ((1ull << lane) - 1ull));
            float sd  = stds[a];
            float var = sd * sd;
            float k   = -0.72134752044448f / var;              // -0.5*log2(e)/var
            float c2  = __log2f(dens[a] * 0.15915494309189535f / var); // log2(coef)
            satom[pos] = make_float4(x, y, k, c2);
        }
        __syncthreads();

        const int cnt = s_cnt;
        for (int i = 0; i < cnt; ++i) {
            float4 at = satom[i];                 // broadcast LDS read
            float dx = pxf - at.x;
            float dy = pyf - at.y;
            float s2 = fmaf(dy, dy, dx * dx);
            acc += exp2f(fmaf(s2, at.z, at.w));   // coef * exp(ninv*r^2)
        }
        __syncthreads();
    }

    atomicAdd(&out[((size_t)b * S + py) * S + px], acc);
}

extern "C" void kernel_launch(void* const* d_in, const int* in_sizes, int n_in,
                              void* d_out, int out_size, void* d_ws, size_t ws_size,
                              hipStream_t stream) {
    const float* mol  = (const float*)d_in[0];
    const float* stds = (const float*)d_in[1];
    const float* dens = (const float*)d_in[2];
    float* out = (float*)d_out;

    const int A = in_sizes[1];             // 20000
    const int B = in_sizes[0] / (A * 3);   // 16

    hipMemsetAsync(d_out, 0, (size_t)out_size * sizeof(float), stream);
    proj_gather<<<dim3(NTILE, NS, B), dim3(BLOCK), 0, stream>>>(mol, stds, dens, out, A);
}

// Round 3
// 266.996 us; speedup vs baseline: 2.6020x; 1.0052x over previous
//
#include <hip/hip_runtime.h>

// Gather with wave-split inner loop.
// Block = (batch, 16x16 tile, atom-split). Scan+ballot-compact surviving atoms
// into LDS (as R2). Inner loop: each wave owns every 4th atom and covers ALL
// 256 tile pixels with 4 px/lane -> 4x fewer wave-iters and ds_reads than R2,
// with explicit prefetch + 4 independent exp2 chains to tolerate LDS latency
// (R2's serial ds_read->wait->compute loop at 2.5 waves/SIMD gave 46% VALUBusy).

#define S 128
#define TS 16
#define TPS (S / TS)            // 8 tiles per side
#define NTILE (TPS * TPS)       // 64
#define NS 8                    // atom-splits per tile (load balance)
#define BLOCK 256
#define NWAVE (BLOCK / 64)
#define RAD 6.5f                // truncation: err ~ 8*exp(-6.5^2/4.5) ~ 7e-4 << 0.235

__global__ __launch_bounds__(BLOCK) void proj_gather(
    const float* __restrict__ mol,   // (B, A, 3)
    const float* __restrict__ stds,  // (A)
    const float* __restrict__ dens,  // (A)
    float* __restrict__ out,         // (B, S, S) fp32, pre-zeroed
    int A)
{
    __shared__ float4 satom[BLOCK];  // compacted (x, y, k, c2)
    __shared__ int s_cnt;

    const int tile  = blockIdx.x;
    const int split = blockIdx.y;
    const int b     = blockIdx.z;

    const int tx0 = (tile & (TPS - 1)) * TS;
    const int ty0 = (tile / TPS) * TS;
    const int tid  = threadIdx.x;
    const int lane = tid & 63;
    const int wav  = tid >> 6;

    // 4 px/lane: column = lane&15, rows = (lane>>4) + 4j
    const int col  = lane & (TS - 1);
    const int row0 = lane >> 4;                   // 0..3
    const float pxf = (float)(tx0 + col) - 63.5f;
    const float pyf0 = (float)(ty0 + row0) - 63.5f;

    // tile bbox in atom space, expanded by RAD
    const float xlo = (float)tx0 - 63.5f - RAD;
    const float xhi = (float)(tx0 + TS - 1) - 63.5f + RAD;
    const float ylo = (float)ty0 - 63.5f - RAD;
    const float yhi = (float)(ty0 + TS - 1) - 63.5f + RAD;

    const int per = (A + NS - 1) / NS;
    const int a0 = split * per;
    const int a1 = min(a0 + per, A);
    const size_t molbase = (size_t)b * A;

    float acc0 = 0.0f, acc1 = 0.0f, acc2 = 0.0f, acc3 = 0.0f;

    for (int base = a0; base < a1; base += BLOCK) {
        if (tid == 0) s_cnt = 0;
        __syncthreads();

        const int a = base + tid;
        bool ok = false;
        float x = 0.0f, y = 0.0f;
        if (a < a1) {
            x = mol[(molbase + a) * 3 + 0];
            y = mol[(molbase + a) * 3 + 1];
            ok = (x >= xlo) && (x <= xhi) && (y >= ylo) && (y <= yhi);
        }

        unsigned long long m = __ballot(ok);
        int wb = 0;
        if (lane == 0 && m) wb = atomicAdd(&s_cnt, __popcll(m));
        wb = __shfl(wb, 0);
        if (ok) {
            int pos = wb + __popcll(m & ((1ull << lane) - 1ull));
            float sd  = stds[a];
            float var = sd * sd;
            float k   = -0.72134752044448f / var;                      // -0.5*log2e/var
            float c2  = __log2f(dens[a] * 0.15915494309189535f / var); // log2(coef)
            satom[pos] = make_float4(x, y, k, c2);
        }
        __syncthreads();

        const int cnt = s_cnt;

        // wave-split: wave w handles atoms w, w+4, ... ; each wave covers all
        // 256 pixels (4 rows per lane, stride 4).
        int i = wav;
        float4 at = satom[(i < BLOCK) ? i : 0];   // prefetch (in-bounds always)
        for (; i < cnt; i += NWAVE) {
            float4 nx = satom[(i + NWAVE < BLOCK) ? (i + NWAVE) : 0]; // prefetch next
            float dx  = pxf - at.x;
            float dx2 = dx * dx;
            float dy0 = pyf0         - at.y;
            float dy1 = pyf0 +  4.0f - at.y;
            float dy2 = pyf0 +  8.0f - at.y;
            float dy3 = pyf0 + 12.0f - at.y;
            float e0 = exp2f(fmaf(fmaf(dy0, dy0, dx2), at.z, at.w));
            float e1 = exp2f(fmaf(fmaf(dy1, dy1, dx2), at.z, at.w));
            float e2 = exp2f(fmaf(fmaf(dy2, dy2, dx2), at.z, at.w));
            float e3 = exp2f(fmaf(fmaf(dy3, dy3, dx2), at.z, at.w));
            acc0 += e0; acc1 += e1; acc2 += e2; acc3 += e3;
            at = nx;
        }
        __syncthreads();
    }

    // merge NS partial tiles
    const size_t ob = ((size_t)b * S + (ty0 + row0)) * S + (tx0 + col);
    atomicAdd(&out[ob + 0 * 4 * S], acc0);
    atomicAdd(&out[ob + 1 * 4 * S], acc1);
    atomicAdd(&out[ob + 2 * 4 * S], acc2);
    atomicAdd(&out[ob + 3 * 4 * S], acc3);
}

extern "C" void kernel_launch(void* const* d_in, const int* in_sizes, int n_in,
                              void* d_out, int out_size, void* d_ws, size_t ws_size,
                              hipStream_t stream) {
    const float* mol  = (const float*)d_in[0];
    const float* stds = (const float*)d_in[1];
    const float* dens = (const float*)d_in[2];
    float* out = (float*)d_out;

    const int A = in_sizes[1];             // 20000
    const int B = in_sizes[0] / (A * 3);   // 16

    hipMemsetAsync(d_out, 0, (size_t)out_size * sizeof(float), stream);
    proj_gather<<<dim3(NTILE, NS, B), dim3(BLOCK), 0, stream>>>(mol, stds, dens, out, A);
}